// Round 14
// baseline (657.866 us; speedup 1.0000x reference)
//
#include <hip/hip_runtime.h>
#include <hip/hip_fp16.h>
#include <cstdint>
#include <cstddef>

#define NN   200000
#define HH   128
#define BB   1024
#define LL   50
#define NNZK 3200000
#define RPBK 200      // rows per bucket
#define NBK  1000     // buckets (RPBK*NBK == NN)
#define MSB  256      // multi-split blocks
#define CHUNK (NNZK/MSB)   // 12500 entries per block
#define SK   8        // split-K for line matmuls

typedef unsigned int uint32;
typedef unsigned short ushort16;
typedef __attribute__((ext_vector_type(8))) short bf16x8;
typedef __attribute__((ext_vector_type(4))) float f32x4;
union U8 { uint32 u[4]; bf16x8 v; };

#if defined(__has_builtin)
#if __has_builtin(__builtin_amdgcn_cvt_pk_f32_fp8) && __has_builtin(__builtin_amdgcn_cvt_pk_fp8_f32)
#define HW_FP8 1
#endif
#endif
#ifndef HW_FP8
#define HW_FP8 0
#endif

// ---------- bf16 pack/unpack helpers (RNE) ----------
__device__ __forceinline__ uint32 f2bf2(float a, float b){
  uint32 ua=__float_as_uint(a), ub=__float_as_uint(b);
  ua = (ua + 0x7FFFu + ((ua>>16)&1u)) >> 16;
  ub = (ub + 0x7FFFu + ((ub>>16)&1u)) >> 16;
  return ua | (ub<<16);
}
__device__ __forceinline__ float2 bf2x2f(uint32 u){
  return make_float2(__uint_as_float(u<<16), __uint_as_float(u & 0xFFFF0000u));
}

// ---------- fp8 e4m3 helpers ----------
#if !HW_FP8
__device__ __forceinline__ uint32 enc8_sw(float f){
  ushort16 b = __half_as_ushort(__float2half_rn(f*0.00390625f));
  uint32 t = b & 0x7FFFu;
  uint32 r = (t + 0x3Fu + ((t>>7)&1u)) >> 7;
  if(r > 0x7Eu) r = 0x7Eu;
  return ((b>>8)&0x80u) | r;
}
#endif

__device__ __forceinline__ float2 fp8x2f(uint32 s){   // 2 fp8 in low 16 bits
#if HW_FP8
  auto r = __builtin_amdgcn_cvt_pk_f32_fp8((int)s, false);
  return make_float2(r[0], r[1]);
#else
  union{uint32 u; __half2 h;} cv;
  cv.u = ((s&0x80u)<<8)|((s&0x7Fu)<<7) | ((s&0x8000u)<<16)|((s&0x7F00u)<<15);
  float2 f = __half22float2(cv.h);
  return make_float2(f.x*256.f, f.y*256.f);
#endif
}

__device__ __forceinline__ ushort16 f2fp8x2(float a, float b){
#if HW_FP8
  return (ushort16)__builtin_amdgcn_cvt_pk_fp8_f32(a, b, 0, false);
#else
  return (ushort16)(enc8_sw(a) | (enc8_sw(b)<<8));
#endif
}

__device__ __forceinline__ uint32 f2fp8x4(float4 v){
#if HW_FP8
  int p = __builtin_amdgcn_cvt_pk_fp8_f32(v.x, v.y, 0, false);
  p = __builtin_amdgcn_cvt_pk_fp8_f32(v.z, v.w, p, true);
  return (uint32)p;
#else
  return enc8_sw(v.x) | (enc8_sw(v.y)<<8) | (enc8_sw(v.z)<<16) | (enc8_sw(v.w)<<24);
#endif
}

// ---------- fused: items f32 -> bf16+fp8 (blocks >= MSB) ; bucket hist (blocks < MSB) ----------
__global__ __launch_bounds__(256) void k_cvt_bhist(const float* __restrict__ x,
    uint32* __restrict__ obf, uint32* __restrict__ o8,
    const int* __restrict__ rows, int* __restrict__ bhist, int* __restrict__ bh2){
  if(blockIdx.x < MSB){
    __shared__ int h[NBK];
    for(int b=threadIdx.x;b<NBK;b+=256) h[b]=0;
    __syncthreads();
    const int i0=blockIdx.x*CHUNK;
    for(int i=i0+threadIdx.x;i<i0+CHUNK;i+=256) atomicAdd(&h[rows[i]/RPBK],1);
    __syncthreads();
    for(int b=threadIdx.x;b<NBK;b+=256){
      int c=h[b];
      bh2[blockIdx.x*NBK+b]=c;
      if(c) atomicAdd(&bhist[b],c);
    }
  } else {
    const int n = NN*32;
    const int nb = gridDim.x - MSB;
    for(int i=(blockIdx.x-MSB)*256+threadIdx.x; i<n; i+=nb*256){
      float4 v = ((const float4*)x)[i];
      obf[2*i]   = f2bf2(v.x, v.y);
      obf[2*i+1] = f2bf2(v.z, v.w);
      o8[i] = f2fp8x4(v);
    }
  }
}

__global__ __launch_bounds__(1024) void k_bscan(const int* __restrict__ bhist,
    int* __restrict__ bstart, int* __restrict__ bcur){
  __shared__ int s[1024];
  int t=threadIdx.x;
  int v=(t<NBK)?bhist[t]:0;
  s[t]=v;
  __syncthreads();
  for(int off=1;off<1024;off<<=1){
    int u=(t>=off)?s[t-off]:0; __syncthreads(); s[t]+=u; __syncthreads();
  }
  if(t<NBK){ int e=s[t]-v; bstart[t]=e; bcur[t]=e; }
}

// multi-split: reuse precomputed per-block hist -> reserve -> ranged scatter
__global__ __launch_bounds__(256) void k_msplit(const int* __restrict__ rows,
    const int* __restrict__ cols, const float* __restrict__ vals,
    const int* __restrict__ bh2, int* __restrict__ bcur, int2* __restrict__ bpk){
  __shared__ int hist[NBK];
  __shared__ int rbase[NBK];
  const int tid=threadIdx.x;
  const int i0=blockIdx.x*CHUNK, i1=i0+CHUNK;
  for(int b=tid;b<NBK;b+=256){
    int c=bh2[blockIdx.x*NBK+b];
    rbase[b] = c ? atomicAdd(&bcur[b],c) : 0;
    hist[b]=0;
  }
  __syncthreads();
  for(int i=i0+tid;i<i1;i+=256){
    int r=rows[i];
    int b=r/RPBK, ro=r-b*RPBK;
    int p = rbase[b] + atomicAdd(&hist[b],1);
    bpk[p]=make_int2(cols[i] | (ro<<18), __float_as_int(vals[i]));
  }
}

// pass 2: per-bucket row-sort; writes rp; pk.x stored as BYTE offset (col*128)
__global__ __launch_bounds__(256) void k_bucket_sort(const int2* __restrict__ bpk,
    const int* __restrict__ bstart, const int* __restrict__ bhist,
    int2* __restrict__ pk, int* __restrict__ rp){
  __shared__ int cnt[RPBK];
  __shared__ int sc[256];
  int b=blockIdx.x, t=threadIdx.x;
  int base=bstart[b], total=bhist[b];
  if(t<RPBK) cnt[t]=0;
  __syncthreads();
  for(int j=t;j<total;j+=256) atomicAdd(&cnt[((uint32)bpk[base+j].x)>>18],1);
  __syncthreads();
  int myc=(t<RPBK)?cnt[t]:0;
  sc[t]=myc;
  __syncthreads();
  for(int off=1;off<256;off<<=1){
    int u=(t>=off)?sc[t-off]:0; __syncthreads(); sc[t]+=u; __syncthreads();
  }
  int excl = sc[t]-myc;
  __syncthreads();
  if(t<RPBK){ cnt[t]=base+excl; rp[b*RPBK+t]=base+excl; }
  if(b==0 && t==0) rp[NN]=NNZK;
  __syncthreads();
  for(int j=t;j<total;j+=256){
    int2 e=bpk[base+j];
    int ro=((uint32)e.x)>>18;
    int p=atomicAdd(&cnt[ro],1);
    pk[p]=make_int2((e.x&0x3FFFF)<<7, e.y);   // byte offset (row stride 128B)
  }
}

// ---------------- quad-row SpMM body: 4 nnz per gather instruction ----------------
// lane group g (lane>>4) handles nnz j+g; each lane reads 8B (8 fp8) at col goff=(lane&15)*8.
// ax[0..7] = partial sums for columns goff..goff+7 over this group's nnz subset.
__device__ __forceinline__ void q_acc(float* ax, uint2 e, float v){
  float2 f0=fp8x2f(e.x), f1=fp8x2f(e.x>>16);
  float2 f2=fp8x2f(e.y), f3=fp8x2f(e.y>>16);
  ax[0]=fmaf(v,f0.x,ax[0]); ax[1]=fmaf(v,f0.y,ax[1]);
  ax[2]=fmaf(v,f1.x,ax[2]); ax[3]=fmaf(v,f1.y,ax[3]);
  ax[4]=fmaf(v,f2.x,ax[4]); ax[5]=fmaf(v,f2.y,ax[5]);
  ax[6]=fmaf(v,f3.x,ax[6]); ax[7]=fmaf(v,f3.y,ax[7]);
}

__device__ __forceinline__ void spmm_body_q(const int2* __restrict__ pk, int j0, int j1,
    const char* __restrict__ src, int goff, int grp, float* ax){
  int j  = __builtin_amdgcn_readfirstlane(j0);
  int jE = __builtin_amdgcn_readfirstlane(j1);
  for(; j+16<=jE; j+=16){          // 16 nnz = 4 gather instrs
    int2 p[4]; uint2 e[4];
    #pragma unroll
    for(int u=0;u<4;++u) p[u]=pk[j+4*u+grp];
    #pragma unroll
    for(int u=0;u<4;++u) e[u]=*(const uint2*)(src + (uint32)p[u].x + goff);
    #pragma unroll
    for(int u=0;u<4;++u) q_acc(ax, e[u], __int_as_float(p[u].y));
  }
  for(; j+4<=jE; j+=4){
    int2 p=pk[j+grp];
    uint2 e=*(const uint2*)(src + (uint32)p.x + goff);
    q_acc(ax, e, __int_as_float(p.y));
  }
  int rem = jE - j;
  if(rem>0){                       // 1..3 tail: idle groups read j with weight 0
    int jj = j + (grp<rem ? grp : 0);
    int2 p=pk[jj];
    float v = (grp<rem) ? __int_as_float(p.y) : 0.f;
    uint2 e=*(const uint2*)(src + (uint32)p.x + goff);
    q_acc(ax, e, v);
  }
}

__device__ __forceinline__ void q_reduce(float* ax){
  #pragma unroll
  for(int k=0;k<8;++k){
    ax[k] += __shfl_xor(ax[k],16);
    ax[k] += __shfl_xor(ax[k],32);
  }
}

__global__ __launch_bounds__(256) void k_spmm_b(
    const int2* __restrict__ pk, const int* __restrict__ rp,
    const char* __restrict__ src, uint32* __restrict__ dst)
{
  int wid = blockIdx.x*4 + (threadIdx.x>>6);
  int lane = threadIdx.x & 63;
  if(wid>=NN) return;
  int grp=lane>>4, goff=(lane&15)*8;
  float ax[8]={0,0,0,0,0,0,0,0};
  spmm_body_q(pk, rp[wid], rp[wid+1], src, goff, grp, ax);
  q_reduce(ax);
  if(grp==0){
    uint2 o;
    o.x=f2fp8x4(make_float4(ax[0],ax[1],ax[2],ax[3]));
    o.y=f2fp8x4(make_float4(ax[4],ax[5],ax[6],ax[7]));
    *(uint2*)((char*)dst + (size_t)wid*128 + goff) = o;
  }
}

// final: e3 = A@B(fp8) ; acc=(x_bf16 + e1 + e2 + e3)*0.25 -> hgout(f32) + hgbf(packed bf16)
// NOTE: xbf aliases obf (itbf) — same-element read/write by same thread only.
__global__ __launch_bounds__(256) void k_spmm_final(
    const int2* __restrict__ pk, const int* __restrict__ rp,
    const char* __restrict__ A8, const char* __restrict__ B8,
    const uint32* xbf, float* __restrict__ acc, uint32* obf)
{
  int wid = blockIdx.x*4 + (threadIdx.x>>6);
  int lane = threadIdx.x & 63;
  if(wid>=NN) return;
  int grp=lane>>4, goff=(lane&15)*8;
  float ax[8]={0,0,0,0,0,0,0,0};
  spmm_body_q(pk, rp[wid], rp[wid+1], B8, goff, grp, ax);
  q_reduce(ax);
  if(grp==0){
    uint2 e1=*(const uint2*)(A8 + (size_t)wid*128 + goff);
    uint2 e2=*(const uint2*)(B8 + (size_t)wid*128 + goff);
    float2 a0=fp8x2f(e1.x), a1=fp8x2f(e1.x>>16), a2=fp8x2f(e1.y), a3=fp8x2f(e1.y>>16);
    float2 b0=fp8x2f(e2.x), b1=fp8x2f(e2.x>>16), b2=fp8x2f(e2.y), b3=fp8x2f(e2.y>>16);
    int xi = wid*64 + (lane&15)*4;       // 4 u32 of bf16 pairs = 8 cols
    uint32 x0=xbf[xi], x1=xbf[xi+1], x2=xbf[xi+2], x3=xbf[xi+3];
    float2 xv0=bf2x2f(x0), xv1=bf2x2f(x1), xv2=bf2x2f(x2), xv3=bf2x2f(x3);
    float r0=(xv0.x+a0.x+b0.x+ax[0])*0.25f, r1=(xv0.y+a0.y+b0.y+ax[1])*0.25f;
    float r2=(xv1.x+a1.x+b1.x+ax[2])*0.25f, r3=(xv1.y+a1.y+b1.y+ax[3])*0.25f;
    float r4=(xv2.x+a2.x+b2.x+ax[4])*0.25f, r5=(xv2.y+a2.y+b2.y+ax[5])*0.25f;
    float r6=(xv3.x+a3.x+b3.x+ax[6])*0.25f, r7=(xv3.y+a3.y+b3.y+ax[7])*0.25f;
    size_t ao=(size_t)wid*128 + (lane&15)*8;
    acc[ao]=r0; acc[ao+1]=r1; acc[ao+2]=r2; acc[ao+3]=r3;
    acc[ao+4]=r4; acc[ao+5]=r5; acc[ao+6]=r6; acc[ao+7]=r7;
    obf[xi]  =f2bf2(r0,r1); obf[xi+1]=f2bf2(r2,r3);
    obf[xi+2]=f2bf2(r4,r5); obf[xi+3]=f2bf2(r6,r7);
  }
}

// ---------------- fused: sessline (items,sinfo) + sess_mean/sm2 (hgbf,rinfo) + posW1 ----------------
__global__ __launch_bounds__(128) void k_sessmean2(const uint32* __restrict__ hgbf,
    const int* __restrict__ rev, const int* __restrict__ slen,
    const float* __restrict__ w2, const float* __restrict__ b2, float* __restrict__ sm2,
    const float* __restrict__ pos_table, const float* __restrict__ w1W,
    const float* __restrict__ w1b0, float* __restrict__ posW1,
    const float* __restrict__ items, const int* __restrict__ sinfo,
    float* __restrict__ cur, float* __restrict__ accL){
  __shared__ float sm[HH];
  int b=blockIdx.x, h=threadIdx.x;
  int hw=h>>1, hi=h&1;
  float sl=1.f/(float)slen[b];
  {
    float s=0.f;
    for(int l=0;l<LL;++l){
      int idx=sinfo[b*LL+l];
      if(idx>0 && idx<=NN) s += items[(size_t)(idx-1)*HH+h];
    }
    s *= sl;
    cur[(size_t)b*HH+h]=s; accL[(size_t)b*HH+h]=s;
  }
  float s=0.f;
  for(int l=0;l<LL;++l){
    int idx=rev[b*LL+l];
    if(idx>0 && idx<=NN){
      float2 f=bf2x2f(hgbf[(size_t)(idx-1)*64+hw]);
      s += hi ? f.y : f.x;
    }
  }
  sm[h]=s*sl;
  __syncthreads();
  float a=b2[h];
  for(int k=0;k<HH;++k) a=fmaf(sm[k], w2[k*HH+h], a);
  sm2[b*HH+h]=a;
  if(b<LL){
    float pa=w1b0[h];
    for(int k=0;k<HH;++k) pa=fmaf(pos_table[b*HH+k], w1W[k*HH+h], pa);
    posW1[b*HH+h]=pa;
  }
}

// ---------------- MFMA GEMM 1: ns = tanh(posW1[l] + gather(hgbf) @ w1seq) ----------------
#define AS 69
#define BS 67
__global__ __launch_bounds__(256) void k_nsgemm(
    const uint32* __restrict__ hgbf, const int* __restrict__ rev,
    const float* __restrict__ w1b, const float* __restrict__ posW1,
    float* __restrict__ ns)
{
  __shared__ uint32 sA[64*AS];
  __shared__ uint32 sB[128*BS];
  const int tid=threadIdx.x;
  {
    int r=tid>>2, p=tid&3;
    int idx = rev[blockIdx.x*64 + r];
    if(idx>0 && idx<=NN){
      const uint32* s = hgbf + (size_t)(idx-1)*64 + p*16;
      #pragma unroll
      for(int j=0;j<16;++j) sA[r*AS+p*16+j]=s[j];
    } else {
      #pragma unroll
      for(int j=0;j<16;++j) sA[r*AS+p*16+j]=0u;
    }
  }
  for(int i=tid;i<128*64;i+=256){
    int n=i&127, kp=i>>7;
    sB[n*BS+kp]=f2bf2(w1b[(2*kp)*HH+n], w1b[(2*kp+1)*HH+n]);
  }
  __syncthreads();
  const int w=tid>>6, lane=tid&63, g=lane>>4, m15=lane&15;
  f32x4 acc[8];
  #pragma unroll
  for(int nt=0;nt<8;++nt) acc[nt]=(f32x4){0.f,0.f,0.f,0.f};
  #pragma unroll
  for(int kt=0;kt<4;++kt){
    U8 a;
    int ab=(w*16+m15)*AS + kt*16 + g*4;
    a.u[0]=sA[ab]; a.u[1]=sA[ab+1]; a.u[2]=sA[ab+2]; a.u[3]=sA[ab+3];
    #pragma unroll
    for(int nt=0;nt<8;++nt){
      U8 b;
      int bb=(nt*16+m15)*BS + kt*16 + g*4;
      b.u[0]=sB[bb]; b.u[1]=sB[bb+1]; b.u[2]=sB[bb+2]; b.u[3]=sB[bb+3];
      acc[nt]=__builtin_amdgcn_mfma_f32_16x16x32_bf16(a.v,b.v,acc[nt],0,0,0);
    }
  }
  int rowbase = blockIdx.x*64 + w*16 + g*4;
  #pragma unroll
  for(int r=0;r<4;++r){
    int gr=rowbase+r;
    int l=gr%LL;
    #pragma unroll
    for(int nt=0;nt<8;++nt){
      int col=nt*16+m15;
      ns[(size_t)gr*HH+col] = tanhf(acc[nt][r] + posW1[l*HH+col]);
    }
  }
}

// ---------------- MFMA GEMM 2: alpha = sum_h sigmoid(sm2[b]+ns@w3+b3)*fT ----------------
__global__ __launch_bounds__(256) void k_agemm(
    const float* __restrict__ ns, const float* __restrict__ w3,
    const float* __restrict__ sm2, const float* __restrict__ b3,
    const float* __restrict__ fT, float* __restrict__ alpha)
{
  __shared__ uint32 sA[64*AS];
  __shared__ uint32 sB[128*BS];
  const int tid=threadIdx.x;
  {
    int r=tid>>2, p=tid&3;
    const float2* s = (const float2*)(ns + (size_t)(blockIdx.x*64+r)*HH + p*32);
    #pragma unroll
    for(int j=0;j<16;++j){ float2 f=s[j]; sA[r*AS+p*16+j]=f2bf2(f.x,f.y); }
  }
  for(int i=tid;i<128*64;i+=256){
    int n=i&127, kp=i>>7;
    sB[n*BS+kp]=f2bf2(w3[(2*kp)*HH+n], w3[(2*kp+1)*HH+n]);
  }
  __syncthreads();
  const int w=tid>>6, lane=tid&63, g=lane>>4, m15=lane&15;
  f32x4 acc[8];
  #pragma unroll
  for(int nt=0;nt<8;++nt) acc[nt]=(f32x4){0.f,0.f,0.f,0.f};
  #pragma unroll
  for(int kt=0;kt<4;++kt){
    U8 a;
    int ab=(w*16+m15)*AS + kt*16 + g*4;
    a.u[0]=sA[ab]; a.u[1]=sA[ab+1]; a.u[2]=sA[ab+2]; a.u[3]=sA[ab+3];
    #pragma unroll
    for(int nt=0;nt<8;++nt){
      U8 b;
      int bb=(nt*16+m15)*BS + kt*16 + g*4;
      b.u[0]=sB[bb]; b.u[1]=sB[bb+1]; b.u[2]=sB[bb+2]; b.u[3]=sB[bb+3];
      acc[nt]=__builtin_amdgcn_mfma_f32_16x16x32_bf16(a.v,b.v,acc[nt],0,0,0);
    }
  }
  int rowbase = blockIdx.x*64 + w*16 + g*4;
  #pragma unroll
  for(int r=0;r<4;++r){
    int gr=rowbase+r;
    int b_=gr/LL;
    float rsum=0.f;
    #pragma unroll
    for(int nt=0;nt<8;++nt){
      int col=nt*16+m15;
      float gv = acc[nt][r] + sm2[b_*HH+col] + b3[col];
      rsum += fT[col] / (1.f + expf(-gv));
    }
    rsum += __shfl_xor(rsum,1);
    rsum += __shfl_xor(rsum,2);
    rsum += __shfl_xor(rsum,4);
    rsum += __shfl_xor(rsum,8);
    if(m15==0) alpha[gr]=rsum;
  }
}

// ---------------- theta ----------------
__global__ __launch_bounds__(128) void k_theta(const float* __restrict__ ns,
    const float* __restrict__ alpha, float* __restrict__ hg_sess){
  __shared__ float sal[64];
  int b=blockIdx.x, h=threadIdx.x;
  if(h<LL) sal[h]=alpha[b*LL+h];
  __syncthreads();
  float t=0.f;
  for(int l=0;l<LL;++l) t=fmaf(sal[l], ns[((size_t)b*LL+l)*HH+h], t);
  hg_sess[(size_t)b*HH+h]=t;
}

// part[kc] = M[:,kc*128:+128] @ src[kc*128:+128,:]  (SK=8)
__global__ __launch_bounds__(128) void k_matpart(const float* __restrict__ M,
    const float* __restrict__ src, float* __restrict__ part){
  int rq = blockIdx.x >> 3;
  int kc = blockIdx.x & 7;
  int h = threadIdx.x;
  int r0 = rq*4;
  const int KC = BB/SK;
  const float* m0 = M + (size_t)r0*BB + kc*KC;
  const float* m1 = m0 + BB;
  const float* m2 = m1 + BB;
  const float* m3 = m2 + BB;
  const float* s0 = src + (size_t)kc*KC*HH + h;
  float a0=0,a1=0,a2=0,a3=0;
  for(int k=0;k<KC;++k){
    float s=s0[(size_t)k*HH];
    a0=fmaf(m0[k],s,a0); a1=fmaf(m1[k],s,a1);
    a2=fmaf(m2[k],s,a2); a3=fmaf(m3[k],s,a3);
  }
  size_t o=(size_t)kc*BB*HH + (size_t)r0*HH + h;
  part[o]=a0; part[o+HH]=a1; part[o+2*HH]=a2; part[o+3*HH]=a3;
}

__global__ __launch_bounds__(256) void k_matcomb(const float* __restrict__ part,
    float* __restrict__ dst, float* __restrict__ acc, int mode){
  int i = blockIdx.x*256+threadIdx.x;
  const int S = BB*HH;
  float v = 0.f;
  #pragma unroll
  for(int kc=0;kc<SK;++kc) v += part[i+(size_t)kc*S];
  dst[i]=v;
  if(mode==1) acc[i]+=v;
  else if(mode==2) acc[i]=(acc[i]+v)*0.25f;
}

// ---------------- SSL loss (deterministic two-stage) ----------------
__global__ __launch_bounds__(128) void k_ssl(const float* __restrict__ hg,
    const float* __restrict__ line, const int* __restrict__ pr,
    const int* __restrict__ pc, float* __restrict__ part){
  int b=blockIdx.x, h=threadIdx.x;
  __shared__ float sp[2][2];
  float lv = line[(size_t)b*HH+h];
  float v1 = hg[(size_t)b*HH+h]*lv;
  float v2 = hg[(size_t)pr[b]*HH + pc[h]]*lv;
  for(int o=32;o>0;o>>=1){ v1+=__shfl_xor(v1,o); v2+=__shfl_xor(v2,o); }
  int wv=h>>6, ln=h&63;
  if(ln==0){ sp[0][wv]=v1; sp[1][wv]=v2; }
  __syncthreads();
  if(h==0){
    float pos=sp[0][0]+sp[0][1];
    float neg=sp[1][0]+sp[1][1];
    float sigp=1.f/(1.f+expf(-pos));
    float sign_=1.f/(1.f+expf(-neg));
    part[b] = -logf(1e-8f+sigp) - logf(1e-8f+(1.f-sign_));
  }
}

__global__ __launch_bounds__(256) void k_red(const float* __restrict__ part, float* __restrict__ loss){
  __shared__ float s[256];
  int t=threadIdx.x;
  s[t]=part[t]+part[t+256]+part[t+512]+part[t+768];
  __syncthreads();
  for(int o=128;o>0;o>>=1){ if(t<o) s[t]+=s[t+o]; __syncthreads(); }
  if(t==0) *loss = 0.01f*s[0];
}

extern "C" void kernel_launch(void* const* d_in, const int* in_sizes, int n_in,
                              void* d_out, int out_size, void* d_ws, size_t ws_size,
                              hipStream_t stream){
  const float* items    =(const float*)d_in[0];
  const float* pos_table=(const float*)d_in[1];
  const float* w1W      =(const float*)d_in[2];
  const float* w1b_     =(const float*)d_in[3];
  const float* w2W      =(const float*)d_in[4];
  const float* w2b      =(const float*)d_in[5];
  const float* w3W      =(const float*)d_in[6];
  const float* w3b      =(const float*)d_in[7];
  const float* fT       =(const float*)d_in[8];
  const float* hvals    =(const float*)d_in[9];
  const float* lineA    =(const float*)d_in[10];
  const float* degD     =(const float*)d_in[11];
  const int*   hrows    =(const int*)d_in[12];
  const int*   hcols    =(const int*)d_in[13];
  const int*   sinfo    =(const int*)d_in[14];   // int64 in ref -> int32 in harness
  const int*   rinfo    =(const int*)d_in[15];
  const int*   slen     =(const int*)d_in[16];
  const int*   prow     =(const int*)d_in[18];
  const int*   pcol     =(const int*)d_in[19];

  float* outf   = (float*)d_out;
  float* hg_sess= outf;
  float* loss   = outf + (size_t)BB*HH;
  float* hgout  = outf + (size_t)BB*HH + 1;    // hg_item (4B-aligned only)

  char* base=(char*)d_ws; size_t off=0;
  auto carve=[&](size_t bytes)->char*{ char* p=base+off; off=(off+bytes+255)&~(size_t)255; return p; };

  float*    posW1 =(float*)   carve((size_t)LL*HH*4);
  float*    curA  =(float*)   carve((size_t)BB*HH*4);
  float*    curB  =(float*)   carve((size_t)BB*HH*4);
  float*    tmpv  =(float*)   carve((size_t)BB*HH*4);
  float*    accL  =(float*)   carve((size_t)BB*HH*4);
  float*    lpart =(float*)   carve((size_t)BB*4);
  float*    mpart =(float*)   carve((size_t)SK*BB*HH*4);
  int2*     pk    =(int2*)    carve((size_t)NNZK*8);
  int*      rp    =(int*)     carve((size_t)(NN+1)*4);
  int*      bhist =(int*)     carve((size_t)NBK*4);
  int*      bstart=(int*)     carve((size_t)NBK*4);
  int*      bcur  =(int*)     carve((size_t)NBK*4);
  int*      bh2   =(int*)     carve((size_t)MSB*NBK*4);
  uint32*   itbf  =(uint32*)  carve((size_t)NN*64*4);   // bf16 items / later hgbf
  uint32*   it8   =(uint32*)  carve((size_t)NN*32*4);   // fp8 items
  char*     A8    =(char*)    carve((size_t)NN*128);    // fp8 e1
  char*     B8    =(char*)    carve((size_t)NN*128);    // fp8 e2
  if(off > ws_size) return;

  // overlays: bpk lives in A8 region during CSR build;
  // after spmm_final: itbf -> hgbf; A8 -> ns; then alpha/sm2
  int2*   bpk   = (int2*)A8;
  uint32* hgbf  = itbf;
  float*  ns    = (float*)A8;
  float*  alpha = ns + (size_t)BB*LL*HH;
  float*  sm2   = alpha + (size_t)BB*LL;

  // fused cvt + bucket hist
  hipMemsetAsync(bhist,0,(size_t)NBK*4,stream);
  k_cvt_bhist<<<MSB+2048,256,0,stream>>>(items,itbf,it8,hrows,bhist,bh2);
  k_bscan<<<1,1024,0,stream>>>(bhist,bstart,bcur);
  k_msplit<<<MSB,256,0,stream>>>(hrows,hcols,hvals,bh2,bcur,bpk);
  k_bucket_sort<<<NBK,256,0,stream>>>(bpk,bstart,bhist,pk,rp);

  // hypergraph conv (fp8 quad-row gather chain)
  k_spmm_b    <<<NN/4,256,0,stream>>>(pk,rp, (const char*)it8, (uint32*)A8);
  k_spmm_b    <<<NN/4,256,0,stream>>>(pk,rp, A8, (uint32*)B8);
  k_spmm_final<<<NN/4,256,0,stream>>>(pk,rp, A8, B8, itbf, hgout, hgbf);

  // session attention + line-graph session means (fused)
  k_sessmean2<<<BB,HH,0,stream>>>(hgbf,rinfo,slen,w2W,w2b,sm2,
                                  pos_table,w1W,w1b_,posW1,
                                  items,sinfo,curA,accL);
  k_nsgemm   <<<(BB*LL)/64,256,0,stream>>>(hgbf,rinfo,w1W+HH*HH,posW1,ns);
  k_agemm    <<<(BB*LL)/64,256,0,stream>>>(ns,w3W,sm2,w3b,fT,alpha);
  k_theta    <<<BB,HH,0,stream>>>(ns,alpha,hg_sess);

  // line graph conv
  for(int s=0;s<3;++s){
    float* srcv=(s&1)?curB:curA;
    float* dstv=(s&1)?curA:curB;
    k_matpart<<<(BB/4)*SK,128,0,stream>>>(lineA,srcv,mpart);
    k_matcomb<<<BB*HH/256,256,0,stream>>>(mpart,tmpv,nullptr,0);
    k_matpart<<<(BB/4)*SK,128,0,stream>>>(degD,tmpv,mpart);
    k_matcomb<<<BB*HH/256,256,0,stream>>>(mpart,dstv,accL,(s==2)?2:1);
  }

  // SSL loss
  k_ssl<<<BB,HH,0,stream>>>(hg_sess,accL,prow,pcol,lpart);
  k_red<<<1,256,0,stream>>>(lpart,loss);
}

// Round 15
// 602.920 us; speedup vs baseline: 1.0911x; 1.0911x over previous
//
#include <hip/hip_runtime.h>
#include <hip/hip_fp16.h>
#include <cstdint>
#include <cstddef>

#define NN   200000
#define HH   128
#define BB   1024
#define LL   50
#define NNZK 3200000
#define RPBK 200      // rows per bucket
#define NBK  1000     // buckets (RPBK*NBK == NN)
#define MSB  256      // multi-split blocks
#define CHUNK (NNZK/MSB)   // 12500 entries per block
#define SK   8        // split-K for line matmuls

typedef unsigned int uint32;
typedef unsigned short ushort16;
typedef __attribute__((ext_vector_type(8))) short bf16x8;
typedef __attribute__((ext_vector_type(4))) float f32x4;
union U8 { uint32 u[4]; bf16x8 v; };

#if defined(__has_builtin)
#if __has_builtin(__builtin_amdgcn_cvt_pk_f32_fp8) && __has_builtin(__builtin_amdgcn_cvt_pk_fp8_f32)
#define HW_FP8 1
#endif
#endif
#ifndef HW_FP8
#define HW_FP8 0
#endif

// ---------- bf16 pack/unpack helpers (RNE) ----------
__device__ __forceinline__ uint32 f2bf2(float a, float b){
  uint32 ua=__float_as_uint(a), ub=__float_as_uint(b);
  ua = (ua + 0x7FFFu + ((ua>>16)&1u)) >> 16;
  ub = (ub + 0x7FFFu + ((ub>>16)&1u)) >> 16;
  return ua | (ub<<16);
}
__device__ __forceinline__ float2 bf2x2f(uint32 u){
  return make_float2(__uint_as_float(u<<16), __uint_as_float(u & 0xFFFF0000u));
}

// ---------- fp8 e4m3 helpers ----------
#if !HW_FP8
__device__ __forceinline__ uint32 enc8_sw(float f){
  ushort16 b = __half_as_ushort(__float2half_rn(f*0.00390625f));
  uint32 t = b & 0x7FFFu;
  uint32 r = (t + 0x3Fu + ((t>>7)&1u)) >> 7;
  if(r > 0x7Eu) r = 0x7Eu;
  return ((b>>8)&0x80u) | r;
}
#endif

__device__ __forceinline__ float2 fp8x2f(uint32 s){   // 2 fp8 in low 16 bits
#if HW_FP8
  auto r = __builtin_amdgcn_cvt_pk_f32_fp8((int)s, false);
  return make_float2(r[0], r[1]);
#else
  union{uint32 u; __half2 h;} cv;
  cv.u = ((s&0x80u)<<8)|((s&0x7Fu)<<7) | ((s&0x8000u)<<16)|((s&0x7F00u)<<15);
  float2 f = __half22float2(cv.h);
  return make_float2(f.x*256.f, f.y*256.f);
#endif
}

__device__ __forceinline__ ushort16 f2fp8x2(float a, float b){
#if HW_FP8
  return (ushort16)__builtin_amdgcn_cvt_pk_fp8_f32(a, b, 0, false);
#else
  return (ushort16)(enc8_sw(a) | (enc8_sw(b)<<8));
#endif
}

__device__ __forceinline__ uint32 f2fp8x4(float4 v){
#if HW_FP8
  int p = __builtin_amdgcn_cvt_pk_fp8_f32(v.x, v.y, 0, false);
  p = __builtin_amdgcn_cvt_pk_fp8_f32(v.z, v.w, p, true);
  return (uint32)p;
#else
  return enc8_sw(v.x) | (enc8_sw(v.y)<<8) | (enc8_sw(v.z)<<16) | (enc8_sw(v.w)<<24);
#endif
}

// ---------- fused: items f32 -> bf16+fp8 (blocks >= MSB) ; bucket hist (blocks < MSB) ----------
__global__ __launch_bounds__(256) void k_cvt_bhist(const float* __restrict__ x,
    uint32* __restrict__ obf, uint32* __restrict__ o8,
    const int* __restrict__ rows, int* __restrict__ bhist, int* __restrict__ bh2){
  if(blockIdx.x < MSB){
    __shared__ int h[NBK];
    for(int b=threadIdx.x;b<NBK;b+=256) h[b]=0;
    __syncthreads();
    const int i0=blockIdx.x*CHUNK;
    for(int i=i0+threadIdx.x;i<i0+CHUNK;i+=256) atomicAdd(&h[rows[i]/RPBK],1);
    __syncthreads();
    for(int b=threadIdx.x;b<NBK;b+=256){
      int c=h[b];
      bh2[blockIdx.x*NBK+b]=c;
      if(c) atomicAdd(&bhist[b],c);
    }
  } else {
    const int n = NN*32;
    const int nb = gridDim.x - MSB;
    for(int i=(blockIdx.x-MSB)*256+threadIdx.x; i<n; i+=nb*256){
      float4 v = ((const float4*)x)[i];
      obf[2*i]   = f2bf2(v.x, v.y);
      obf[2*i+1] = f2bf2(v.z, v.w);
      o8[i] = f2fp8x4(v);
    }
  }
}

__global__ __launch_bounds__(1024) void k_bscan(const int* __restrict__ bhist,
    int* __restrict__ bstart, int* __restrict__ bcur){
  __shared__ int s[1024];
  int t=threadIdx.x;
  int v=(t<NBK)?bhist[t]:0;
  s[t]=v;
  __syncthreads();
  for(int off=1;off<1024;off<<=1){
    int u=(t>=off)?s[t-off]:0; __syncthreads(); s[t]+=u; __syncthreads();
  }
  if(t<NBK){ int e=s[t]-v; bstart[t]=e; bcur[t]=e; }
}

// multi-split: reuse precomputed per-block hist -> reserve -> ranged scatter
__global__ __launch_bounds__(256) void k_msplit(const int* __restrict__ rows,
    const int* __restrict__ cols, const float* __restrict__ vals,
    const int* __restrict__ bh2, int* __restrict__ bcur, int2* __restrict__ bpk){
  __shared__ int hist[NBK];
  __shared__ int rbase[NBK];
  const int tid=threadIdx.x;
  const int i0=blockIdx.x*CHUNK, i1=i0+CHUNK;
  for(int b=tid;b<NBK;b+=256){
    int c=bh2[blockIdx.x*NBK+b];
    rbase[b] = c ? atomicAdd(&bcur[b],c) : 0;
    hist[b]=0;
  }
  __syncthreads();
  for(int i=i0+tid;i<i1;i+=256){
    int r=rows[i];
    int b=r/RPBK, ro=r-b*RPBK;
    int p = rbase[b] + atomicAdd(&hist[b],1);
    bpk[p]=make_int2(cols[i] | (ro<<18), __float_as_int(vals[i]));
  }
}

// pass 2: per-bucket row-sort; writes rp; pk.x stored as BYTE offset (col*128)
__global__ __launch_bounds__(256) void k_bucket_sort(const int2* __restrict__ bpk,
    const int* __restrict__ bstart, const int* __restrict__ bhist,
    int2* __restrict__ pk, int* __restrict__ rp){
  __shared__ int cnt[RPBK];
  __shared__ int sc[256];
  int b=blockIdx.x, t=threadIdx.x;
  int base=bstart[b], total=bhist[b];
  if(t<RPBK) cnt[t]=0;
  __syncthreads();
  for(int j=t;j<total;j+=256) atomicAdd(&cnt[((uint32)bpk[base+j].x)>>18],1);
  __syncthreads();
  int myc=(t<RPBK)?cnt[t]:0;
  sc[t]=myc;
  __syncthreads();
  for(int off=1;off<256;off<<=1){
    int u=(t>=off)?sc[t-off]:0; __syncthreads(); sc[t]+=u; __syncthreads();
  }
  int excl = sc[t]-myc;
  __syncthreads();
  if(t<RPBK){ cnt[t]=base+excl; rp[b*RPBK+t]=base+excl; }
  if(b==0 && t==0) rp[NN]=NNZK;
  __syncthreads();
  for(int j=t;j<total;j+=256){
    int2 e=bpk[base+j];
    int ro=((uint32)e.x)>>18;
    int p=atomicAdd(&cnt[ro],1);
    pk[p]=make_int2((e.x&0x3FFFF)<<7, e.y);   // byte offset (row stride 128B)
  }
}

// ---------------- SpMM body: fp8 src, SGPR-uniform pk loads, 16/8/4 unroll ----------------
__device__ __forceinline__ void spmm_body(const int2* __restrict__ pk, int j0, int j1,
    const char* __restrict__ src, int lane2, float& ax, float& ay){
  // loop bounds are per-wave uniform; readfirstlane lets the compiler prove it
  // -> s_load for pk batches, SGPR-base global_load for gathers
  int j  = __builtin_amdgcn_readfirstlane(j0);
  int jE = __builtin_amdgcn_readfirstlane(j1);
  for(; j+16<=jE; j+=16){
    int2 p[16]; ushort16 e[16];
    #pragma unroll
    for(int u=0;u<16;++u) p[u]=pk[j+u];
    #pragma unroll
    for(int u=0;u<16;++u) e[u]=*(const ushort16*)(src + (uint32)__builtin_amdgcn_readfirstlane(p[u].x) + lane2);
    #pragma unroll
    for(int u=0;u<16;++u){
      float2 f=fp8x2f(e[u]);
      float v=__int_as_float(p[u].y);
      ax=fmaf(v,f.x,ax); ay=fmaf(v,f.y,ay);
    }
  }
  for(; j+8<=jE; j+=8){
    int2 p[8]; ushort16 e[8];
    #pragma unroll
    for(int u=0;u<8;++u) p[u]=pk[j+u];
    #pragma unroll
    for(int u=0;u<8;++u) e[u]=*(const ushort16*)(src + (uint32)__builtin_amdgcn_readfirstlane(p[u].x) + lane2);
    #pragma unroll
    for(int u=0;u<8;++u){
      float2 f=fp8x2f(e[u]);
      float v=__int_as_float(p[u].y);
      ax=fmaf(v,f.x,ax); ay=fmaf(v,f.y,ay);
    }
  }
  for(; j+4<=jE; j+=4){
    int2 p[4]; ushort16 e[4];
    #pragma unroll
    for(int u=0;u<4;++u) p[u]=pk[j+u];
    #pragma unroll
    for(int u=0;u<4;++u) e[u]=*(const ushort16*)(src + (uint32)__builtin_amdgcn_readfirstlane(p[u].x) + lane2);
    #pragma unroll
    for(int u=0;u<4;++u){
      float2 f=fp8x2f(e[u]);
      float v=__int_as_float(p[u].y);
      ax=fmaf(v,f.x,ax); ay=fmaf(v,f.y,ay);
    }
  }
  for(; j<jE; ++j){
    int2 p=pk[j];
    float2 f=fp8x2f(*(const ushort16*)(src + (uint32)__builtin_amdgcn_readfirstlane(p.x) + lane2));
    float v=__int_as_float(p.y);
    ax=fmaf(v,f.x,ax); ay=fmaf(v,f.y,ay);
  }
}

__global__ __launch_bounds__(256) void k_spmm_b(
    const int2* __restrict__ pk, const int* __restrict__ rp,
    const ushort16* __restrict__ src, ushort16* __restrict__ dst)
{
  int wid = blockIdx.x*4 + (threadIdx.x>>6);
  int lane = threadIdx.x & 63;
  if(wid>=NN) return;
  float ax=0.f, ay=0.f;
  spmm_body(pk, rp[wid], rp[wid+1], (const char*)src, lane*2, ax, ay);
  dst[(size_t)wid*64+lane]=f2fp8x2(ax,ay);
}

// final: e3 = A@B(fp8) ; acc=(x_bf16 + e1 + e2 + e3)*0.25 -> hgout(f32) + hgbf(packed bf16)
// NOTE: xbf aliases obf (itbf) — same-element read/write by same thread only.
__global__ __launch_bounds__(256) void k_spmm_final(
    const int2* __restrict__ pk, const int* __restrict__ rp,
    const ushort16* __restrict__ A8, const ushort16* __restrict__ B8,
    const uint32* xbf, float* __restrict__ acc, uint32* obf)
{
  int wid = blockIdx.x*4 + (threadIdx.x>>6);
  int lane = threadIdx.x & 63;
  if(wid>=NN) return;
  float ax=0.f, ay=0.f;
  spmm_body(pk, rp[wid], rp[wid+1], (const char*)B8, lane*2, ax, ay);
  float2 xv  = bf2x2f(xbf[(size_t)wid*64+lane]);
  float2 e1v = fp8x2f(A8[(size_t)wid*64+lane]);
  float2 e2v = fp8x2f(B8[(size_t)wid*64+lane]);
  size_t ao=(size_t)wid*128 + lane*2;
  float rx = (xv.x + e1v.x + e2v.x + ax)*0.25f;
  float ry = (xv.y + e1v.y + e2v.y + ay)*0.25f;
  acc[ao]=rx; acc[ao+1]=ry;
  obf[(size_t)wid*64+lane]=f2bf2(rx,ry);
}

// ---------------- fused: sessline (items,sinfo) + sess_mean/sm2 (hgbf,rinfo) + posW1 ----------------
__global__ __launch_bounds__(128) void k_sessmean2(const uint32* __restrict__ hgbf,
    const int* __restrict__ rev, const int* __restrict__ slen,
    const float* __restrict__ w2, const float* __restrict__ b2, float* __restrict__ sm2,
    const float* __restrict__ pos_table, const float* __restrict__ w1W,
    const float* __restrict__ w1b0, float* __restrict__ posW1,
    const float* __restrict__ items, const int* __restrict__ sinfo,
    float* __restrict__ cur, float* __restrict__ accL){
  __shared__ float sm[HH];
  int b=blockIdx.x, h=threadIdx.x;
  int hw=h>>1, hi=h&1;
  float sl=1.f/(float)slen[b];
  // line-graph session mean (f32 items, sinfo)
  {
    float s=0.f;
    for(int l=0;l<LL;++l){
      int idx=sinfo[b*LL+l];
      if(idx>0 && idx<=NN) s += items[(size_t)(idx-1)*HH+h];
    }
    s *= sl;
    cur[(size_t)b*HH+h]=s; accL[(size_t)b*HH+h]=s;
  }
  // hypergraph session mean (bf16 hgbf, rinfo) -> sm2 GEMV
  float s=0.f;
  for(int l=0;l<LL;++l){
    int idx=rev[b*LL+l];
    if(idx>0 && idx<=NN){
      float2 f=bf2x2f(hgbf[(size_t)(idx-1)*64+hw]);
      s += hi ? f.y : f.x;
    }
  }
  sm[h]=s*sl;
  __syncthreads();
  float a=b2[h];
  for(int k=0;k<HH;++k) a=fmaf(sm[k], w2[k*HH+h], a);
  sm2[b*HH+h]=a;
  if(b<LL){
    float pa=w1b0[h];
    for(int k=0;k<HH;++k) pa=fmaf(pos_table[b*HH+k], w1W[k*HH+h], pa);
    posW1[b*HH+h]=pa;
  }
}

// ---------------- MFMA GEMM 1: ns = tanh(posW1[l] + gather(hgbf) @ w1seq) ----------------
#define AS 69
#define BS 67
__global__ __launch_bounds__(256) void k_nsgemm(
    const uint32* __restrict__ hgbf, const int* __restrict__ rev,
    const float* __restrict__ w1b, const float* __restrict__ posW1,
    float* __restrict__ ns)
{
  __shared__ uint32 sA[64*AS];
  __shared__ uint32 sB[128*BS];
  const int tid=threadIdx.x;
  {
    int r=tid>>2, p=tid&3;
    int idx = rev[blockIdx.x*64 + r];
    if(idx>0 && idx<=NN){
      const uint32* s = hgbf + (size_t)(idx-1)*64 + p*16;
      #pragma unroll
      for(int j=0;j<16;++j) sA[r*AS+p*16+j]=s[j];
    } else {
      #pragma unroll
      for(int j=0;j<16;++j) sA[r*AS+p*16+j]=0u;
    }
  }
  for(int i=tid;i<128*64;i+=256){
    int n=i&127, kp=i>>7;
    sB[n*BS+kp]=f2bf2(w1b[(2*kp)*HH+n], w1b[(2*kp+1)*HH+n]);
  }
  __syncthreads();
  const int w=tid>>6, lane=tid&63, g=lane>>4, m15=lane&15;
  f32x4 acc[8];
  #pragma unroll
  for(int nt=0;nt<8;++nt) acc[nt]=(f32x4){0.f,0.f,0.f,0.f};
  #pragma unroll
  for(int kt=0;kt<4;++kt){
    U8 a;
    int ab=(w*16+m15)*AS + kt*16 + g*4;
    a.u[0]=sA[ab]; a.u[1]=sA[ab+1]; a.u[2]=sA[ab+2]; a.u[3]=sA[ab+3];
    #pragma unroll
    for(int nt=0;nt<8;++nt){
      U8 b;
      int bb=(nt*16+m15)*BS + kt*16 + g*4;
      b.u[0]=sB[bb]; b.u[1]=sB[bb+1]; b.u[2]=sB[bb+2]; b.u[3]=sB[bb+3];
      acc[nt]=__builtin_amdgcn_mfma_f32_16x16x32_bf16(a.v,b.v,acc[nt],0,0,0);
    }
  }
  int rowbase = blockIdx.x*64 + w*16 + g*4;
  #pragma unroll
  for(int r=0;r<4;++r){
    int gr=rowbase+r;
    int l=gr%LL;
    #pragma unroll
    for(int nt=0;nt<8;++nt){
      int col=nt*16+m15;
      ns[(size_t)gr*HH+col] = tanhf(acc[nt][r] + posW1[l*HH+col]);
    }
  }
}

// ---------------- MFMA GEMM 2: alpha = sum_h sigmoid(sm2[b]+ns@w3+b3)*fT ----------------
__global__ __launch_bounds__(256) void k_agemm(
    const float* __restrict__ ns, const float* __restrict__ w3,
    const float* __restrict__ sm2, const float* __restrict__ b3,
    const float* __restrict__ fT, float* __restrict__ alpha)
{
  __shared__ uint32 sA[64*AS];
  __shared__ uint32 sB[128*BS];
  const int tid=threadIdx.x;
  {
    int r=tid>>2, p=tid&3;
    const float2* s = (const float2*)(ns + (size_t)(blockIdx.x*64+r)*HH + p*32);
    #pragma unroll
    for(int j=0;j<16;++j){ float2 f=s[j]; sA[r*AS+p*16+j]=f2bf2(f.x,f.y); }
  }
  for(int i=tid;i<128*64;i+=256){
    int n=i&127, kp=i>>7;
    sB[n*BS+kp]=f2bf2(w3[(2*kp)*HH+n], w3[(2*kp+1)*HH+n]);
  }
  __syncthreads();
  const int w=tid>>6, lane=tid&63, g=lane>>4, m15=lane&15;
  f32x4 acc[8];
  #pragma unroll
  for(int nt=0;nt<8;++nt) acc[nt]=(f32x4){0.f,0.f,0.f,0.f};
  #pragma unroll
  for(int kt=0;kt<4;++kt){
    U8 a;
    int ab=(w*16+m15)*AS + kt*16 + g*4;
    a.u[0]=sA[ab]; a.u[1]=sA[ab+1]; a.u[2]=sA[ab+2]; a.u[3]=sA[ab+3];
    #pragma unroll
    for(int nt=0;nt<8;++nt){
      U8 b;
      int bb=(nt*16+m15)*BS + kt*16 + g*4;
      b.u[0]=sB[bb]; b.u[1]=sB[bb+1]; b.u[2]=sB[bb+2]; b.u[3]=sB[bb+3];
      acc[nt]=__builtin_amdgcn_mfma_f32_16x16x32_bf16(a.v,b.v,acc[nt],0,0,0);
    }
  }
  int rowbase = blockIdx.x*64 + w*16 + g*4;
  #pragma unroll
  for(int r=0;r<4;++r){
    int gr=rowbase+r;
    int b_=gr/LL;
    float rsum=0.f;
    #pragma unroll
    for(int nt=0;nt<8;++nt){
      int col=nt*16+m15;
      float gv = acc[nt][r] + sm2[b_*HH+col] + b3[col];
      rsum += fT[col] / (1.f + expf(-gv));
    }
    rsum += __shfl_xor(rsum,1);
    rsum += __shfl_xor(rsum,2);
    rsum += __shfl_xor(rsum,4);
    rsum += __shfl_xor(rsum,8);
    if(m15==0) alpha[gr]=rsum;
  }
}

// ---------------- theta ----------------
__global__ __launch_bounds__(128) void k_theta(const float* __restrict__ ns,
    const float* __restrict__ alpha, float* __restrict__ hg_sess){
  __shared__ float sal[64];
  int b=blockIdx.x, h=threadIdx.x;
  if(h<LL) sal[h]=alpha[b*LL+h];
  __syncthreads();
  float t=0.f;
  for(int l=0;l<LL;++l) t=fmaf(sal[l], ns[((size_t)b*LL+l)*HH+h], t);
  hg_sess[(size_t)b*HH+h]=t;
}

// part[kc] = M[:,kc*128:+128] @ src[kc*128:+128,:]  (SK=8)
__global__ __launch_bounds__(128) void k_matpart(const float* __restrict__ M,
    const float* __restrict__ src, float* __restrict__ part){
  int rq = blockIdx.x >> 3;
  int kc = blockIdx.x & 7;
  int h = threadIdx.x;
  int r0 = rq*4;
  const int KC = BB/SK;
  const float* m0 = M + (size_t)r0*BB + kc*KC;
  const float* m1 = m0 + BB;
  const float* m2 = m1 + BB;
  const float* m3 = m2 + BB;
  const float* s0 = src + (size_t)kc*KC*HH + h;
  float a0=0,a1=0,a2=0,a3=0;
  for(int k=0;k<KC;++k){
    float s=s0[(size_t)k*HH];
    a0=fmaf(m0[k],s,a0); a1=fmaf(m1[k],s,a1);
    a2=fmaf(m2[k],s,a2); a3=fmaf(m3[k],s,a3);
  }
  size_t o=(size_t)kc*BB*HH + (size_t)r0*HH + h;
  part[o]=a0; part[o+HH]=a1; part[o+2*HH]=a2; part[o+3*HH]=a3;
}

__global__ __launch_bounds__(256) void k_matcomb(const float* __restrict__ part,
    float* __restrict__ dst, float* __restrict__ acc, int mode){
  int i = blockIdx.x*256+threadIdx.x;
  const int S = BB*HH;
  float v = 0.f;
  #pragma unroll
  for(int kc=0;kc<SK;++kc) v += part[i+(size_t)kc*S];
  dst[i]=v;
  if(mode==1) acc[i]+=v;
  else if(mode==2) acc[i]=(acc[i]+v)*0.25f;
}

// ---------------- SSL loss (deterministic two-stage) ----------------
__global__ __launch_bounds__(128) void k_ssl(const float* __restrict__ hg,
    const float* __restrict__ line, const int* __restrict__ pr,
    const int* __restrict__ pc, float* __restrict__ part){
  int b=blockIdx.x, h=threadIdx.x;
  __shared__ float sp[2][2];
  float lv = line[(size_t)b*HH+h];
  float v1 = hg[(size_t)b*HH+h]*lv;
  float v2 = hg[(size_t)pr[b]*HH + pc[h]]*lv;
  for(int o=32;o>0;o>>=1){ v1+=__shfl_xor(v1,o); v2+=__shfl_xor(v2,o); }
  int wv=h>>6, ln=h&63;
  if(ln==0){ sp[0][wv]=v1; sp[1][wv]=v2; }
  __syncthreads();
  if(h==0){
    float pos=sp[0][0]+sp[0][1];
    float neg=sp[1][0]+sp[1][1];
    float sigp=1.f/(1.f+expf(-pos));
    float sign_=1.f/(1.f+expf(-neg));
    part[b] = -logf(1e-8f+sigp) - logf(1e-8f+(1.f-sign_));
  }
}

__global__ __launch_bounds__(256) void k_red(const float* __restrict__ part, float* __restrict__ loss){
  __shared__ float s[256];
  int t=threadIdx.x;
  s[t]=part[t]+part[t+256]+part[t+512]+part[t+768];
  __syncthreads();
  for(int o=128;o>0;o>>=1){ if(t<o) s[t]+=s[t+o]; __syncthreads(); }
  if(t==0) *loss = 0.01f*s[0];
}

extern "C" void kernel_launch(void* const* d_in, const int* in_sizes, int n_in,
                              void* d_out, int out_size, void* d_ws, size_t ws_size,
                              hipStream_t stream){
  const float* items    =(const float*)d_in[0];
  const float* pos_table=(const float*)d_in[1];
  const float* w1W      =(const float*)d_in[2];
  const float* w1b_     =(const float*)d_in[3];
  const float* w2W      =(const float*)d_in[4];
  const float* w2b      =(const float*)d_in[5];
  const float* w3W      =(const float*)d_in[6];
  const float* w3b      =(const float*)d_in[7];
  const float* fT       =(const float*)d_in[8];
  const float* hvals    =(const float*)d_in[9];
  const float* lineA    =(const float*)d_in[10];
  const float* degD     =(const float*)d_in[11];
  const int*   hrows    =(const int*)d_in[12];
  const int*   hcols    =(const int*)d_in[13];
  const int*   sinfo    =(const int*)d_in[14];   // int64 in ref -> int32 in harness
  const int*   rinfo    =(const int*)d_in[15];
  const int*   slen     =(const int*)d_in[16];
  const int*   prow     =(const int*)d_in[18];
  const int*   pcol     =(const int*)d_in[19];

  float* outf   = (float*)d_out;
  float* hg_sess= outf;
  float* loss   = outf + (size_t)BB*HH;
  float* hgout  = outf + (size_t)BB*HH + 1;    // hg_item (4B-aligned only)

  char* base=(char*)d_ws; size_t off=0;
  auto carve=[&](size_t bytes)->char*{ char* p=base+off; off=(off+bytes+255)&~(size_t)255; return p; };

  float*    posW1 =(float*)   carve((size_t)LL*HH*4);
  float*    curA  =(float*)   carve((size_t)BB*HH*4);
  float*    curB  =(float*)   carve((size_t)BB*HH*4);
  float*    tmpv  =(float*)   carve((size_t)BB*HH*4);
  float*    accL  =(float*)   carve((size_t)BB*HH*4);
  float*    lpart =(float*)   carve((size_t)BB*4);
  float*    mpart =(float*)   carve((size_t)SK*BB*HH*4);
  int2*     pk    =(int2*)    carve((size_t)NNZK*8);
  int*      rp    =(int*)     carve((size_t)(NN+1)*4);
  int*      bhist =(int*)     carve((size_t)NBK*4);
  int*      bstart=(int*)     carve((size_t)NBK*4);
  int*      bcur  =(int*)     carve((size_t)NBK*4);
  int*      bh2   =(int*)     carve((size_t)MSB*NBK*4);
  uint32*   itbf  =(uint32*)  carve((size_t)NN*64*4);   // bf16 items / later hgbf
  uint32*   it8   =(uint32*)  carve((size_t)NN*32*4);   // fp8 items
  ushort16* A8    =(ushort16*)carve((size_t)NN*64*2);   // fp8 e1
  ushort16* B8    =(ushort16*)carve((size_t)NN*64*2);   // fp8 e2
  if(off > ws_size) return;

  // overlays: bpk lives in A8 region during CSR build;
  // after spmm_final: itbf -> hgbf; A8 -> ns; then alpha/sm2
  int2*   bpk   = (int2*)A8;
  uint32* hgbf  = itbf;
  float*  ns    = (float*)A8;
  float*  alpha = ns + (size_t)BB*LL*HH;
  float*  sm2   = alpha + (size_t)BB*LL;

  // fused cvt + bucket hist
  hipMemsetAsync(bhist,0,(size_t)NBK*4,stream);
  k_cvt_bhist<<<MSB+2048,256,0,stream>>>(items,itbf,it8,hrows,bhist,bh2);
  k_bscan<<<1,1024,0,stream>>>(bhist,bstart,bcur);
  k_msplit<<<MSB,256,0,stream>>>(hrows,hcols,hvals,bh2,bcur,bpk);
  k_bucket_sort<<<NBK,256,0,stream>>>(bpk,bstart,bhist,pk,rp);

  // hypergraph conv (fp8 gather chain)
  k_spmm_b    <<<NN/4,256,0,stream>>>(pk,rp, (const ushort16*)it8, A8);
  k_spmm_b    <<<NN/4,256,0,stream>>>(pk,rp, A8, B8);
  k_spmm_final<<<NN/4,256,0,stream>>>(pk,rp, A8, B8, itbf, hgout, hgbf);

  // session attention + line-graph session means (fused)
  k_sessmean2<<<BB,HH,0,stream>>>(hgbf,rinfo,slen,w2W,w2b,sm2,
                                  pos_table,w1W,w1b_,posW1,
                                  items,sinfo,curA,accL);
  k_nsgemm   <<<(BB*LL)/64,256,0,stream>>>(hgbf,rinfo,w1W+HH*HH,posW1,ns);
  k_agemm    <<<(BB*LL)/64,256,0,stream>>>(ns,w3W,sm2,w3b,fT,alpha);
  k_theta    <<<BB,HH,0,stream>>>(ns,alpha,hg_sess);

  // line graph conv
  for(int s=0;s<3;++s){
    float* srcv=(s&1)?curB:curA;
    float* dstv=(s&1)?curA:curB;
    k_matpart<<<(BB/4)*SK,128,0,stream>>>(lineA,srcv,mpart);
    k_matcomb<<<BB*HH/256,256,0,stream>>>(mpart,tmpv,nullptr,0);
    k_matpart<<<(BB/4)*SK,128,0,stream>>>(degD,tmpv,mpart);
    k_matcomb<<<BB*HH/256,256,0,stream>>>(mpart,dstv,accL,(s==2)?2:1);
  }

  // SSL loss
  k_ssl<<<BB,HH,0,stream>>>(hg_sess,accL,prow,pcol,lpart);
  k_red<<<1,256,0,stream>>>(lpart,loss);
}

// Round 16
// 582.142 us; speedup vs baseline: 1.1301x; 1.0357x over previous
//
#include <hip/hip_runtime.h>
#include <hip/hip_fp16.h>
#include <cstdint>
#include <cstddef>

#define NN   200000
#define HH   128
#define BB   1024
#define LL   50
#define NNZK 3200000
#define RPBK 200      // rows per bucket
#define NBK  1000     // buckets (RPBK*NBK == NN)
#define MSB  256      // multi-split blocks
#define CHUNK (NNZK/MSB)   // 12500 entries per block
#define SK   8        // split-K for line matmuls

typedef unsigned int uint32;
typedef unsigned short ushort16;
typedef __attribute__((ext_vector_type(8))) short bf16x8;
typedef __attribute__((ext_vector_type(4))) float f32x4;
union U8 { uint32 u[4]; bf16x8 v; };

#if defined(__has_builtin)
#if __has_builtin(__builtin_amdgcn_cvt_pk_f32_fp8) && __has_builtin(__builtin_amdgcn_cvt_pk_fp8_f32)
#define HW_FP8 1
#endif
#endif
#ifndef HW_FP8
#define HW_FP8 0
#endif

// ---------- bf16 pack/unpack helpers (RNE) ----------
__device__ __forceinline__ uint32 f2bf2(float a, float b){
  uint32 ua=__float_as_uint(a), ub=__float_as_uint(b);
  ua = (ua + 0x7FFFu + ((ua>>16)&1u)) >> 16;
  ub = (ub + 0x7FFFu + ((ub>>16)&1u)) >> 16;
  return ua | (ub<<16);
}
__device__ __forceinline__ float2 bf2x2f(uint32 u){
  return make_float2(__uint_as_float(u<<16), __uint_as_float(u & 0xFFFF0000u));
}

// ---------- fp8 e4m3 helpers ----------
#if !HW_FP8
__device__ __forceinline__ uint32 enc8_sw(float f){
  ushort16 b = __half_as_ushort(__float2half_rn(f*0.00390625f));
  uint32 t = b & 0x7FFFu;
  uint32 r = (t + 0x3Fu + ((t>>7)&1u)) >> 7;
  if(r > 0x7Eu) r = 0x7Eu;
  return ((b>>8)&0x80u) | r;
}
#endif

__device__ __forceinline__ float2 fp8x2f(uint32 s){   // 2 fp8 in low 16 bits
#if HW_FP8
  auto r = __builtin_amdgcn_cvt_pk_f32_fp8((int)s, false);
  return make_float2(r[0], r[1]);
#else
  union{uint32 u; __half2 h;} cv;
  cv.u = ((s&0x80u)<<8)|((s&0x7Fu)<<7) | ((s&0x8000u)<<16)|((s&0x7F00u)<<15);
  float2 f = __half22float2(cv.h);
  return make_float2(f.x*256.f, f.y*256.f);
#endif
}

__device__ __forceinline__ ushort16 f2fp8x2(float a, float b){
#if HW_FP8
  return (ushort16)__builtin_amdgcn_cvt_pk_fp8_f32(a, b, 0, false);
#else
  return (ushort16)(enc8_sw(a) | (enc8_sw(b)<<8));
#endif
}

__device__ __forceinline__ uint32 f2fp8x4(float4 v){
#if HW_FP8
  int p = __builtin_amdgcn_cvt_pk_fp8_f32(v.x, v.y, 0, false);
  p = __builtin_amdgcn_cvt_pk_fp8_f32(v.z, v.w, p, true);
  return (uint32)p;
#else
  return enc8_sw(v.x) | (enc8_sw(v.y)<<8) | (enc8_sw(v.z)<<16) | (enc8_sw(v.w)<<24);
#endif
}

// ---------- fused: items f32 -> bf16+fp8 (blocks >= MSB) ; bucket hist (blocks < MSB) ----------
__global__ __launch_bounds__(256) void k_cvt_bhist(const float* __restrict__ x,
    uint32* __restrict__ obf, uint32* __restrict__ o8,
    const int* __restrict__ rows, int* __restrict__ bhist, int* __restrict__ bh2){
  if(blockIdx.x < MSB){
    __shared__ int h[NBK];
    for(int b=threadIdx.x;b<NBK;b+=256) h[b]=0;
    __syncthreads();
    const int i0=blockIdx.x*CHUNK;
    for(int i=i0+threadIdx.x;i<i0+CHUNK;i+=256) atomicAdd(&h[rows[i]/RPBK],1);
    __syncthreads();
    for(int b=threadIdx.x;b<NBK;b+=256){
      int c=h[b];
      bh2[blockIdx.x*NBK+b]=c;
      if(c) atomicAdd(&bhist[b],c);
    }
  } else {
    const int n = NN*32;
    const int nb = gridDim.x - MSB;
    for(int i=(blockIdx.x-MSB)*256+threadIdx.x; i<n; i+=nb*256){
      float4 v = ((const float4*)x)[i];
      obf[2*i]   = f2bf2(v.x, v.y);
      obf[2*i+1] = f2bf2(v.z, v.w);
      o8[i] = f2fp8x4(v);
    }
  }
}

__global__ __launch_bounds__(1024) void k_bscan(const int* __restrict__ bhist,
    int* __restrict__ bstart, int* __restrict__ bcur){
  __shared__ int s[1024];
  int t=threadIdx.x;
  int v=(t<NBK)?bhist[t]:0;
  s[t]=v;
  __syncthreads();
  for(int off=1;off<1024;off<<=1){
    int u=(t>=off)?s[t-off]:0; __syncthreads(); s[t]+=u; __syncthreads();
  }
  if(t<NBK){ int e=s[t]-v; bstart[t]=e; bcur[t]=e; }
}

// multi-split: reuse precomputed per-block hist -> reserve -> ranged scatter
__global__ __launch_bounds__(256) void k_msplit(const int* __restrict__ rows,
    const int* __restrict__ cols, const float* __restrict__ vals,
    const int* __restrict__ bh2, int* __restrict__ bcur, int2* __restrict__ bpk){
  __shared__ int hist[NBK];
  __shared__ int rbase[NBK];
  const int tid=threadIdx.x;
  const int i0=blockIdx.x*CHUNK, i1=i0+CHUNK;
  for(int b=tid;b<NBK;b+=256){
    int c=bh2[blockIdx.x*NBK+b];
    rbase[b] = c ? atomicAdd(&bcur[b],c) : 0;
    hist[b]=0;
  }
  __syncthreads();
  for(int i=i0+tid;i<i1;i+=256){
    int r=rows[i];
    int b=r/RPBK, ro=r-b*RPBK;
    int p = rbase[b] + atomicAdd(&hist[b],1);
    bpk[p]=make_int2(cols[i] | (ro<<18), __float_as_int(vals[i]));
  }
}

// pass 2: per-bucket row-sort; writes rp; pk.x stored as BYTE offset (col*128)
__global__ __launch_bounds__(256) void k_bucket_sort(const int2* __restrict__ bpk,
    const int* __restrict__ bstart, const int* __restrict__ bhist,
    int2* __restrict__ pk, int* __restrict__ rp){
  __shared__ int cnt[RPBK];
  __shared__ int sc[256];
  int b=blockIdx.x, t=threadIdx.x;
  int base=bstart[b], total=bhist[b];
  if(t<RPBK) cnt[t]=0;
  __syncthreads();
  for(int j=t;j<total;j+=256) atomicAdd(&cnt[((uint32)bpk[base+j].x)>>18],1);
  __syncthreads();
  int myc=(t<RPBK)?cnt[t]:0;
  sc[t]=myc;
  __syncthreads();
  for(int off=1;off<256;off<<=1){
    int u=(t>=off)?sc[t-off]:0; __syncthreads(); sc[t]+=u; __syncthreads();
  }
  int excl = sc[t]-myc;
  __syncthreads();
  if(t<RPBK){ cnt[t]=base+excl; rp[b*RPBK+t]=base+excl; }
  if(b==0 && t==0) rp[NN]=NNZK;
  __syncthreads();
  for(int j=t;j<total;j+=256){
    int2 e=bpk[base+j];
    int ro=((uint32)e.x)>>18;
    int p=atomicAdd(&cnt[ro],1);
    pk[p]=make_int2((e.x&0x3FFFF)<<7, e.y);   // byte offset (row stride 128B)
  }
}

// ---------------- SpMM body: fp8 src, SGPR-uniform pk loads, 16/8/4 unroll ----------------
__device__ __forceinline__ void spmm_body(const int2* __restrict__ pk, int j0, int j1,
    const char* __restrict__ src, int lane2, float& ax, float& ay){
  int j  = __builtin_amdgcn_readfirstlane(j0);
  int jE = __builtin_amdgcn_readfirstlane(j1);
  for(; j+16<=jE; j+=16){
    int2 p[16]; ushort16 e[16];
    #pragma unroll
    for(int u=0;u<16;++u) p[u]=pk[j+u];
    #pragma unroll
    for(int u=0;u<16;++u) e[u]=*(const ushort16*)(src + (uint32)__builtin_amdgcn_readfirstlane(p[u].x) + lane2);
    #pragma unroll
    for(int u=0;u<16;++u){
      float2 f=fp8x2f(e[u]);
      float v=__int_as_float(p[u].y);
      ax=fmaf(v,f.x,ax); ay=fmaf(v,f.y,ay);
    }
  }
  for(; j+8<=jE; j+=8){
    int2 p[8]; ushort16 e[8];
    #pragma unroll
    for(int u=0;u<8;++u) p[u]=pk[j+u];
    #pragma unroll
    for(int u=0;u<8;++u) e[u]=*(const ushort16*)(src + (uint32)__builtin_amdgcn_readfirstlane(p[u].x) + lane2);
    #pragma unroll
    for(int u=0;u<8;++u){
      float2 f=fp8x2f(e[u]);
      float v=__int_as_float(p[u].y);
      ax=fmaf(v,f.x,ax); ay=fmaf(v,f.y,ay);
    }
  }
  for(; j+4<=jE; j+=4){
    int2 p[4]; ushort16 e[4];
    #pragma unroll
    for(int u=0;u<4;++u) p[u]=pk[j+u];
    #pragma unroll
    for(int u=0;u<4;++u) e[u]=*(const ushort16*)(src + (uint32)__builtin_amdgcn_readfirstlane(p[u].x) + lane2);
    #pragma unroll
    for(int u=0;u<4;++u){
      float2 f=fp8x2f(e[u]);
      float v=__int_as_float(p[u].y);
      ax=fmaf(v,f.x,ax); ay=fmaf(v,f.y,ay);
    }
  }
  for(; j<jE; ++j){
    int2 p=pk[j];
    float2 f=fp8x2f(*(const ushort16*)(src + (uint32)__builtin_amdgcn_readfirstlane(p.x) + lane2));
    float v=__int_as_float(p.y);
    ax=fmaf(v,f.x,ax); ay=fmaf(v,f.y,ay);
  }
}

__global__ __launch_bounds__(256) void k_spmm_b(
    const int2* __restrict__ pk, const int* __restrict__ rp,
    const ushort16* __restrict__ src, ushort16* __restrict__ dst)
{
  int wid = blockIdx.x*4 + (threadIdx.x>>6);
  int lane = threadIdx.x & 63;
  if(wid>=NN) return;
  float ax=0.f, ay=0.f;
  spmm_body(pk, rp[wid], rp[wid+1], (const char*)src, lane*2, ax, ay);
  dst[(size_t)wid*64+lane]=f2fp8x2(ax,ay);
}

// final: e3 = A@B(fp8) ; acc=(x_bf16 + e1 + e2 + e3)*0.25 -> hgout(f32) + hgbf(packed bf16)
// NOTE: xbf aliases obf (itbf) — same-element read/write by same thread only.
__global__ __launch_bounds__(256) void k_spmm_final(
    const int2* __restrict__ pk, const int* __restrict__ rp,
    const ushort16* __restrict__ A8, const ushort16* __restrict__ B8,
    const uint32* xbf, float* __restrict__ acc, uint32* obf)
{
  int wid = blockIdx.x*4 + (threadIdx.x>>6);
  int lane = threadIdx.x & 63;
  if(wid>=NN) return;
  float ax=0.f, ay=0.f;
  spmm_body(pk, rp[wid], rp[wid+1], (const char*)B8, lane*2, ax, ay);
  float2 xv  = bf2x2f(xbf[(size_t)wid*64+lane]);
  float2 e1v = fp8x2f(A8[(size_t)wid*64+lane]);
  float2 e2v = fp8x2f(B8[(size_t)wid*64+lane]);
  size_t ao=(size_t)wid*128 + lane*2;
  float rx = (xv.x + e1v.x + e2v.x + ax)*0.25f;
  float ry = (xv.y + e1v.y + e2v.y + ay)*0.25f;
  acc[ao]=rx; acc[ao+1]=ry;
  obf[(size_t)wid*64+lane]=f2bf2(rx,ry);
}

// ---------------- fused: sessline (items,sinfo) + sess_mean/sm2 (hgbf,rinfo) + posW1 ----------------
__global__ __launch_bounds__(128) void k_sessmean2(const uint32* __restrict__ hgbf,
    const int* __restrict__ rev, const int* __restrict__ slen,
    const float* __restrict__ w2, const float* __restrict__ b2, float* __restrict__ sm2,
    const float* __restrict__ pos_table, const float* __restrict__ w1W,
    const float* __restrict__ w1b0, float* __restrict__ posW1,
    const float* __restrict__ items, const int* __restrict__ sinfo,
    float* __restrict__ cur, float* __restrict__ accL){
  __shared__ float sm[HH];
  int b=blockIdx.x, h=threadIdx.x;
  int hw=h>>1, hi=h&1;
  float sl=1.f/(float)slen[b];
  {
    float s=0.f;
    for(int l=0;l<LL;++l){
      int idx=sinfo[b*LL+l];
      if(idx>0 && idx<=NN) s += items[(size_t)(idx-1)*HH+h];
    }
    s *= sl;
    cur[(size_t)b*HH+h]=s; accL[(size_t)b*HH+h]=s;
  }
  float s=0.f;
  for(int l=0;l<LL;++l){
    int idx=rev[b*LL+l];
    if(idx>0 && idx<=NN){
      float2 f=bf2x2f(hgbf[(size_t)(idx-1)*64+hw]);
      s += hi ? f.y : f.x;
    }
  }
  sm[h]=s*sl;
  __syncthreads();
  float a=b2[h];
  for(int k=0;k<HH;++k) a=fmaf(sm[k], w2[k*HH+h], a);
  sm2[b*HH+h]=a;
  if(b<LL){
    float pa=w1b0[h];
    for(int k=0;k<HH;++k) pa=fmaf(pos_table[b*HH+k], w1W[k*HH+h], pa);
    posW1[b*HH+h]=pa;
  }
}

// ---------------- MFMA GEMM 1: ns = tanh(posW1[l] + gather(hgbf) @ w1seq) ----------------
#define AS 69
#define BS 67
__global__ __launch_bounds__(256) void k_nsgemm(
    const uint32* __restrict__ hgbf, const int* __restrict__ rev,
    const float* __restrict__ w1b, const float* __restrict__ posW1,
    float* __restrict__ ns)
{
  __shared__ uint32 sA[64*AS];
  __shared__ uint32 sB[128*BS];
  const int tid=threadIdx.x;
  {
    int r=tid>>2, p=tid&3;
    int idx = rev[blockIdx.x*64 + r];
    if(idx>0 && idx<=NN){
      const uint32* s = hgbf + (size_t)(idx-1)*64 + p*16;
      #pragma unroll
      for(int j=0;j<16;++j) sA[r*AS+p*16+j]=s[j];
    } else {
      #pragma unroll
      for(int j=0;j<16;++j) sA[r*AS+p*16+j]=0u;
    }
  }
  for(int i=tid;i<128*64;i+=256){
    int n=i&127, kp=i>>7;
    sB[n*BS+kp]=f2bf2(w1b[(2*kp)*HH+n], w1b[(2*kp+1)*HH+n]);
  }
  __syncthreads();
  const int w=tid>>6, lane=tid&63, g=lane>>4, m15=lane&15;
  f32x4 acc[8];
  #pragma unroll
  for(int nt=0;nt<8;++nt) acc[nt]=(f32x4){0.f,0.f,0.f,0.f};
  #pragma unroll
  for(int kt=0;kt<4;++kt){
    U8 a;
    int ab=(w*16+m15)*AS + kt*16 + g*4;
    a.u[0]=sA[ab]; a.u[1]=sA[ab+1]; a.u[2]=sA[ab+2]; a.u[3]=sA[ab+3];
    #pragma unroll
    for(int nt=0;nt<8;++nt){
      U8 b;
      int bb=(nt*16+m15)*BS + kt*16 + g*4;
      b.u[0]=sB[bb]; b.u[1]=sB[bb+1]; b.u[2]=sB[bb+2]; b.u[3]=sB[bb+3];
      acc[nt]=__builtin_amdgcn_mfma_f32_16x16x32_bf16(a.v,b.v,acc[nt],0,0,0);
    }
  }
  int rowbase = blockIdx.x*64 + w*16 + g*4;
  #pragma unroll
  for(int r=0;r<4;++r){
    int gr=rowbase+r;
    int l=gr%LL;
    #pragma unroll
    for(int nt=0;nt<8;++nt){
      int col=nt*16+m15;
      ns[(size_t)gr*HH+col] = tanhf(acc[nt][r] + posW1[l*HH+col]);
    }
  }
}

// ---------------- MFMA GEMM 2: alpha = sum_h sigmoid(sm2[b]+ns@w3+b3)*fT ----------------
__global__ __launch_bounds__(256) void k_agemm(
    const float* __restrict__ ns, const float* __restrict__ w3,
    const float* __restrict__ sm2, const float* __restrict__ b3,
    const float* __restrict__ fT, float* __restrict__ alpha)
{
  __shared__ uint32 sA[64*AS];
  __shared__ uint32 sB[128*BS];
  const int tid=threadIdx.x;
  {
    int r=tid>>2, p=tid&3;
    const float2* s = (const float2*)(ns + (size_t)(blockIdx.x*64+r)*HH + p*32);
    #pragma unroll
    for(int j=0;j<16;++j){ float2 f=s[j]; sA[r*AS+p*16+j]=f2bf2(f.x,f.y); }
  }
  for(int i=tid;i<128*64;i+=256){
    int n=i&127, kp=i>>7;
    sB[n*BS+kp]=f2bf2(w3[(2*kp)*HH+n], w3[(2*kp+1)*HH+n]);
  }
  __syncthreads();
  const int w=tid>>6, lane=tid&63, g=lane>>4, m15=lane&15;
  f32x4 acc[8];
  #pragma unroll
  for(int nt=0;nt<8;++nt) acc[nt]=(f32x4){0.f,0.f,0.f,0.f};
  #pragma unroll
  for(int kt=0;kt<4;++kt){
    U8 a;
    int ab=(w*16+m15)*AS + kt*16 + g*4;
    a.u[0]=sA[ab]; a.u[1]=sA[ab+1]; a.u[2]=sA[ab+2]; a.u[3]=sA[ab+3];
    #pragma unroll
    for(int nt=0;nt<8;++nt){
      U8 b;
      int bb=(nt*16+m15)*BS + kt*16 + g*4;
      b.u[0]=sB[bb]; b.u[1]=sB[bb+1]; b.u[2]=sB[bb+2]; b.u[3]=sB[bb+3];
      acc[nt]=__builtin_amdgcn_mfma_f32_16x16x32_bf16(a.v,b.v,acc[nt],0,0,0);
    }
  }
  int rowbase = blockIdx.x*64 + w*16 + g*4;
  #pragma unroll
  for(int r=0;r<4;++r){
    int gr=rowbase+r;
    int b_=gr/LL;
    float rsum=0.f;
    #pragma unroll
    for(int nt=0;nt<8;++nt){
      int col=nt*16+m15;
      float gv = acc[nt][r] + sm2[b_*HH+col] + b3[col];
      rsum += fT[col] / (1.f + expf(-gv));
    }
    rsum += __shfl_xor(rsum,1);
    rsum += __shfl_xor(rsum,2);
    rsum += __shfl_xor(rsum,4);
    rsum += __shfl_xor(rsum,8);
    if(m15==0) alpha[gr]=rsum;
  }
}

// ---------------- theta ----------------
__global__ __launch_bounds__(128) void k_theta(const float* __restrict__ ns,
    const float* __restrict__ alpha, float* __restrict__ hg_sess){
  __shared__ float sal[64];
  int b=blockIdx.x, h=threadIdx.x;
  if(h<LL) sal[h]=alpha[b*LL+h];
  __syncthreads();
  float t=0.f;
  for(int l=0;l<LL;++l) t=fmaf(sal[l], ns[((size_t)b*LL+l)*HH+h], t);
  hg_sess[(size_t)b*HH+h]=t;
}

// ---------------- MFMA line matmul: part[kc] = M[rt*64..][kc*128..] @ src[kc*128..][:] ----------------
// M: BBxBB f32, src: BBxHH f32. Grid: (BB/64)*SK blocks. Same fragment layout as k_agemm.
__global__ __launch_bounds__(256) void k_matmfma(const float* __restrict__ M,
    const float* __restrict__ src, float* __restrict__ part){
  __shared__ uint32 sA[64*AS];
  __shared__ uint32 sB[128*BS];
  const int tid=threadIdx.x;
  const int rt = blockIdx.x >> 3;     // row tile (64 rows)
  const int kc = blockIdx.x & 7;      // K chunk (128)
  { // stage A: 64 rows of M's kc-chunk, f32 -> bf16 pairs along K
    int r=tid>>2, p=tid&3;
    const float2* s = (const float2*)(M + (size_t)(rt*64+r)*BB + kc*128 + p*32);
    #pragma unroll
    for(int j=0;j<16;++j){ float2 f=s[j]; sA[r*AS+p*16+j]=f2bf2(f.x,f.y); }
  }
  // stage B: src chunk [kc*128 .. +128][128], sB[n][kp] = (src[2kp][n], src[2kp+1][n])
  for(int i=tid;i<128*64;i+=256){
    int n=i&127, kp=i>>7;
    const float* s0 = src + (size_t)(kc*128+2*kp)*HH + n;
    sB[n*BS+kp]=f2bf2(s0[0], s0[HH]);
  }
  __syncthreads();
  const int w=tid>>6, lane=tid&63, g=lane>>4, m15=lane&15;
  f32x4 acc[8];
  #pragma unroll
  for(int nt=0;nt<8;++nt) acc[nt]=(f32x4){0.f,0.f,0.f,0.f};
  #pragma unroll
  for(int kt=0;kt<4;++kt){
    U8 a;
    int ab=(w*16+m15)*AS + kt*16 + g*4;
    a.u[0]=sA[ab]; a.u[1]=sA[ab+1]; a.u[2]=sA[ab+2]; a.u[3]=sA[ab+3];
    #pragma unroll
    for(int nt=0;nt<8;++nt){
      U8 b;
      int bb=(nt*16+m15)*BS + kt*16 + g*4;
      b.u[0]=sB[bb]; b.u[1]=sB[bb+1]; b.u[2]=sB[bb+2]; b.u[3]=sB[bb+3];
      acc[nt]=__builtin_amdgcn_mfma_f32_16x16x32_bf16(a.v,b.v,acc[nt],0,0,0);
    }
  }
  int rowbase = rt*64 + w*16 + g*4;
  #pragma unroll
  for(int r=0;r<4;++r){
    int gr=rowbase+r;
    #pragma unroll
    for(int nt=0;nt<8;++nt){
      int col=nt*16+m15;
      part[(size_t)kc*BB*HH + (size_t)gr*HH + col] = acc[nt][r];
    }
  }
}

__global__ __launch_bounds__(256) void k_matcomb(const float* __restrict__ part,
    float* __restrict__ dst, float* __restrict__ acc, int mode){
  int i = blockIdx.x*256+threadIdx.x;
  const int S = BB*HH;
  float v = 0.f;
  #pragma unroll
  for(int kc=0;kc<SK;++kc) v += part[i+(size_t)kc*S];
  dst[i]=v;
  if(mode==1) acc[i]+=v;
  else if(mode==2) acc[i]=(acc[i]+v)*0.25f;
}

// ---------------- SSL loss (deterministic two-stage) ----------------
__global__ __launch_bounds__(128) void k_ssl(const float* __restrict__ hg,
    const float* __restrict__ line, const int* __restrict__ pr,
    const int* __restrict__ pc, float* __restrict__ part){
  int b=blockIdx.x, h=threadIdx.x;
  __shared__ float sp[2][2];
  float lv = line[(size_t)b*HH+h];
  float v1 = hg[(size_t)b*HH+h]*lv;
  float v2 = hg[(size_t)pr[b]*HH + pc[h]]*lv;
  for(int o=32;o>0;o>>=1){ v1+=__shfl_xor(v1,o); v2+=__shfl_xor(v2,o); }
  int wv=h>>6, ln=h&63;
  if(ln==0){ sp[0][wv]=v1; sp[1][wv]=v2; }
  __syncthreads();
  if(h==0){
    float pos=sp[0][0]+sp[0][1];
    float neg=sp[1][0]+sp[1][1];
    float sigp=1.f/(1.f+expf(-pos));
    float sign_=1.f/(1.f+expf(-neg));
    part[b] = -logf(1e-8f+sigp) - logf(1e-8f+(1.f-sign_));
  }
}

__global__ __launch_bounds__(256) void k_red(const float* __restrict__ part, float* __restrict__ loss){
  __shared__ float s[256];
  int t=threadIdx.x;
  s[t]=part[t]+part[t+256]+part[t+512]+part[t+768];
  __syncthreads();
  for(int o=128;o>0;o>>=1){ if(t<o) s[t]+=s[t+o]; __syncthreads(); }
  if(t==0) *loss = 0.01f*s[0];
}

extern "C" void kernel_launch(void* const* d_in, const int* in_sizes, int n_in,
                              void* d_out, int out_size, void* d_ws, size_t ws_size,
                              hipStream_t stream){
  const float* items    =(const float*)d_in[0];
  const float* pos_table=(const float*)d_in[1];
  const float* w1W      =(const float*)d_in[2];
  const float* w1b_     =(const float*)d_in[3];
  const float* w2W      =(const float*)d_in[4];
  const float* w2b      =(const float*)d_in[5];
  const float* w3W      =(const float*)d_in[6];
  const float* w3b      =(const float*)d_in[7];
  const float* fT       =(const float*)d_in[8];
  const float* hvals    =(const float*)d_in[9];
  const float* lineA    =(const float*)d_in[10];
  const float* degD     =(const float*)d_in[11];
  const int*   hrows    =(const int*)d_in[12];
  const int*   hcols    =(const int*)d_in[13];
  const int*   sinfo    =(const int*)d_in[14];   // int64 in ref -> int32 in harness
  const int*   rinfo    =(const int*)d_in[15];
  const int*   slen     =(const int*)d_in[16];
  const int*   prow     =(const int*)d_in[18];
  const int*   pcol     =(const int*)d_in[19];

  float* outf   = (float*)d_out;
  float* hg_sess= outf;
  float* loss   = outf + (size_t)BB*HH;
  float* hgout  = outf + (size_t)BB*HH + 1;    // hg_item (4B-aligned only)

  char* base=(char*)d_ws; size_t off=0;
  auto carve=[&](size_t bytes)->char*{ char* p=base+off; off=(off+bytes+255)&~(size_t)255; return p; };

  float*    posW1 =(float*)   carve((size_t)LL*HH*4);
  float*    curA  =(float*)   carve((size_t)BB*HH*4);
  float*    curB  =(float*)   carve((size_t)BB*HH*4);
  float*    tmpv  =(float*)   carve((size_t)BB*HH*4);
  float*    accL  =(float*)   carve((size_t)BB*HH*4);
  float*    lpart =(float*)   carve((size_t)BB*4);
  float*    mpart =(float*)   carve((size_t)SK*BB*HH*4);
  int2*     pk    =(int2*)    carve((size_t)NNZK*8);
  int*      rp    =(int*)     carve((size_t)(NN+1)*4);
  int*      bhist =(int*)     carve((size_t)NBK*4);
  int*      bstart=(int*)     carve((size_t)NBK*4);
  int*      bcur  =(int*)     carve((size_t)NBK*4);
  int*      bh2   =(int*)     carve((size_t)MSB*NBK*4);
  uint32*   itbf  =(uint32*)  carve((size_t)NN*64*4);   // bf16 items / later hgbf
  uint32*   it8   =(uint32*)  carve((size_t)NN*32*4);   // fp8 items
  ushort16* A8    =(ushort16*)carve((size_t)NN*64*2);   // fp8 e1
  ushort16* B8    =(ushort16*)carve((size_t)NN*64*2);   // fp8 e2
  if(off > ws_size) return;

  // overlays: bpk lives in A8 region during CSR build;
  // after spmm_final: itbf -> hgbf; A8 -> ns; then alpha/sm2
  int2*   bpk   = (int2*)A8;
  uint32* hgbf  = itbf;
  float*  ns    = (float*)A8;
  float*  alpha = ns + (size_t)BB*LL*HH;
  float*  sm2   = alpha + (size_t)BB*LL;

  // fused cvt + bucket hist
  hipMemsetAsync(bhist,0,(size_t)NBK*4,stream);
  k_cvt_bhist<<<MSB+2048,256,0,stream>>>(items,itbf,it8,hrows,bhist,bh2);
  k_bscan<<<1,1024,0,stream>>>(bhist,bstart,bcur);
  k_msplit<<<MSB,256,0,stream>>>(hrows,hcols,hvals,bh2,bcur,bpk);
  k_bucket_sort<<<NBK,256,0,stream>>>(bpk,bstart,bhist,pk,rp);

  // hypergraph conv (fp8 gather chain)
  k_spmm_b    <<<NN/4,256,0,stream>>>(pk,rp, (const ushort16*)it8, A8);
  k_spmm_b    <<<NN/4,256,0,stream>>>(pk,rp, A8, B8);
  k_spmm_final<<<NN/4,256,0,stream>>>(pk,rp, A8, B8, itbf, hgout, hgbf);

  // session attention + line-graph session means (fused)
  k_sessmean2<<<BB,HH,0,stream>>>(hgbf,rinfo,slen,w2W,w2b,sm2,
                                  pos_table,w1W,w1b_,posW1,
                                  items,sinfo,curA,accL);
  k_nsgemm   <<<(BB*LL)/64,256,0,stream>>>(hgbf,rinfo,w1W+HH*HH,posW1,ns);
  k_agemm    <<<(BB*LL)/64,256,0,stream>>>(ns,w3W,sm2,w3b,fT,alpha);
  k_theta    <<<BB,HH,0,stream>>>(ns,alpha,hg_sess);

  // line graph conv (MFMA split-K GEMMs)
  for(int s=0;s<3;++s){
    float* srcv=(s&1)?curB:curA;
    float* dstv=(s&1)?curA:curB;
    k_matmfma<<<(BB/64)*SK,256,0,stream>>>(lineA,srcv,mpart);
    k_matcomb<<<BB*HH/256,256,0,stream>>>(mpart,tmpv,nullptr,0);
    k_matmfma<<<(BB/64)*SK,256,0,stream>>>(degD,tmpv,mpart);
    k_matcomb<<<BB*HH/256,256,0,stream>>>(mpart,dstv,accL,(s==2)?2:1);
  }

  // SSL loss
  k_ssl<<<BB,HH,0,stream>>>(hg_sess,accL,prow,pcol,lpart);
  k_red<<<1,256,0,stream>>>(lpart,loss);
}